// Round 2
// baseline (415.509 us; speedup 1.0000x reference)
//
#include <hip/hip_runtime.h>
#include <hip/hip_bf16.h>

#define D_BLADE 256
#define D_FFN 1024
#define N_TOK 8192
#define M_TOTAL (N_TOK * 8)

#define BM 64
#define SNP 264   // sN row stride: 528B = 33 16B-slots (odd mod 8 -> uniform slot spread)
#define SHP 136   // sH row stride: 272B = 17 16B-slots
#define FC 128    // F per chunk

typedef __attribute__((ext_vector_type(8))) short bf16x8;
typedef __attribute__((ext_vector_type(4))) float f32x4;

__device__ __forceinline__ float sigm(float v) { return 1.0f / (1.0f + __expf(-v)); }

// ---------------- weights fp32 -> bf16 ----------------
__global__ __launch_bounds__(256) void wconv_kernel(const float* __restrict__ g,
                                                    const float* __restrict__ u,
                                                    const float* __restrict__ dn,
                                                    __hip_bfloat16* __restrict__ gb,
                                                    __hip_bfloat16* __restrict__ ub,
                                                    __hip_bfloat16* __restrict__ db) {
    int i = blockIdx.x * 256 + threadIdx.x;
    gb[i] = __float2bfloat16(g[i]);
    ub[i] = __float2bfloat16(u[i]);
    db[i] = __float2bfloat16(dn[i]);
}

// ---------------- geometric product + mix + LayerNorm -> normed (bf16) ----------------
__global__ __launch_bounds__(256) void geo_ln_kernel(
    const float* __restrict__ x, const float* __restrict__ iw,
    const float* __restrict__ sg, const float* __restrict__ gg,
    const float* __restrict__ lnw, const float* __restrict__ lnb,
    __hip_bfloat16* __restrict__ nrm)
{
    static constexpr int CK[64] = {
        0,1,2,3,4,5,6,7,
        1,0,4,5,2,3,7,6,
        2,4,0,6,1,7,3,5,
        3,5,6,0,7,1,2,4,
        4,2,1,7,0,6,5,3,
        5,3,7,1,6,0,4,2,
        6,7,3,2,5,4,0,1,
        7,6,5,4,3,2,1,0};
    __shared__ float coefs[64];
    __shared__ float redA[4][8];
    __shared__ float redB[4][8];
    const int tid = threadIdx.x;
    const int n = blockIdx.x;
    if (tid < 64) coefs[tid] = sg[tid] * sigm(iw[tid]);
    __syncthreads();

    const float* xp = x + (size_t)n * (8 * D_BLADE) + tid;
    float xa[8];
#pragma unroll
    for (int b = 0; b < 8; ++b) xa[b] = xp[b * D_BLADE];

    float geo[8] = {0.f,0.f,0.f,0.f,0.f,0.f,0.f,0.f};
#pragma unroll
    for (int p = 0; p < 64; ++p)
        geo[CK[p]] += coefs[p] * xa[p >> 3] * xa[p & 7];

    const float g = sigm(gg[0]);
    float mixed[8], sm[8], sq[8];
#pragma unroll
    for (int b = 0; b < 8; ++b) {
        mixed[b] = g * geo[b] + (1.0f - g) * xa[b];
        sm[b] = mixed[b];
        sq[b] = mixed[b] * mixed[b];
    }
#pragma unroll
    for (int off = 32; off > 0; off >>= 1) {
#pragma unroll
        for (int b = 0; b < 8; ++b) {
            sm[b] += __shfl_xor(sm[b], off, 64);
            sq[b] += __shfl_xor(sq[b], off, 64);
        }
    }
    const int wv = tid >> 6;
    if ((tid & 63) == 0) {
#pragma unroll
        for (int b = 0; b < 8; ++b) { redA[wv][b] = sm[b]; redB[wv][b] = sq[b]; }
    }
    __syncthreads();

    const float lw = lnw[tid], lb = lnb[tid];
    __hip_bfloat16* op = nrm + ((size_t)n * 8) * D_BLADE + tid;
#pragma unroll
    for (int b = 0; b < 8; ++b) {
        float ts = redA[0][b] + redA[1][b] + redA[2][b] + redA[3][b];
        float tq = redB[0][b] + redB[1][b] + redB[2][b] + redB[3][b];
        float mu = ts * (1.0f / 256.0f);
        float var = tq * (1.0f / 256.0f) - mu * mu;
        float rs = rsqrtf(var + 1e-5f);
        op[b * D_BLADE] = __float2bfloat16((mixed[b] - mu) * rs * lw + lb);
    }
}

// ---------------- fused SwiGLU FFN + residual ----------------
// 512 threads = 8 waves as (wm,wn) = (2,4). Per wave: M=32 (2 mt), phase2 F=32 (2 ft, gate+up),
// phase3 N=64 (4 nt). Region structure per chunk: [bar][write sH][bar][phase3(c) || phase2(c+1)]
__global__ __launch_bounds__(512, 4) void ffn_kernel(
    const __hip_bfloat16* __restrict__ nrm,
    const __hip_bfloat16* __restrict__ gw,
    const __hip_bfloat16* __restrict__ uw,
    const __hip_bfloat16* __restrict__ dw,
    const float* __restrict__ x,
    float* __restrict__ out)
{
    __shared__ __hip_bfloat16 sN[BM][SNP];
    __shared__ __hip_bfloat16 sH[BM][SHP];
    const int tid = threadIdx.x;
    const int l = tid & 63;
    const int w = tid >> 6;
    const int wm = w >> 2;        // 0..1
    const int wn = w & 3;         // 0..3
    const int rr = l & 15;
    const int kq = l >> 4;        // 0..3
    const int kr = kq * 8;
    const int m0 = blockIdx.x * BM;

    // stage normed 64x256 bf16 tile
#pragma unroll
    for (int it = 0; it < 4; ++it) {
        int idx = it * 4096 + tid * 8;
        int r = idx >> 8, c2 = idx & 255;
        bf16x8 v = *reinterpret_cast<const bf16x8*>(nrm + (size_t)(m0 + r) * D_BLADE + c2);
        *reinterpret_cast<bf16x8*>(&sN[r][c2]) = v;
    }

    const f32x4 zero = {0.f, 0.f, 0.f, 0.f};
    f32x4 acc_o[2][4];
#pragma unroll
    for (int mt = 0; mt < 2; ++mt)
#pragma unroll
        for (int nt = 0; nt < 4; ++nt) acc_o[mt][nt] = zero;

    f32x4 hg[2][2], hu[2][2];

    // ---- phase2 compute: gate/up MFMAs for chunk fc into hg/hu (no sH access) ----
    auto p2compute = [&](int fc) {
#pragma unroll
        for (int mt = 0; mt < 2; ++mt)
#pragma unroll
            for (int ft = 0; ft < 2; ++ft) { hg[mt][ft] = zero; hu[mt][ft] = zero; }
        const __hip_bfloat16* gR = gw + (size_t)(fc * FC + wn * 32 + rr) * D_BLADE + kr;
        const __hip_bfloat16* uR = uw + (size_t)(fc * FC + wn * 32 + rr) * D_BLADE + kr;
#pragma unroll
        for (int kk = 0; kk < 8; ++kk) {
            bf16x8 bg0 = *reinterpret_cast<const bf16x8*>(gR + kk * 32);
            bf16x8 bg1 = *reinterpret_cast<const bf16x8*>(gR + 16 * D_BLADE + kk * 32);
            bf16x8 bu0 = *reinterpret_cast<const bf16x8*>(uR + kk * 32);
            bf16x8 bu1 = *reinterpret_cast<const bf16x8*>(uR + 16 * D_BLADE + kk * 32);
#pragma unroll
            for (int mt = 0; mt < 2; ++mt) {
                bf16x8 a = *reinterpret_cast<const bf16x8*>(&sN[wm * 32 + mt * 16 + rr][kk * 32 + kr]);
                hg[mt][0] = __builtin_amdgcn_mfma_f32_16x16x32_bf16(a, bg0, hg[mt][0], 0, 0, 0);
                hu[mt][0] = __builtin_amdgcn_mfma_f32_16x16x32_bf16(a, bu0, hu[mt][0], 0, 0, 0);
                hg[mt][1] = __builtin_amdgcn_mfma_f32_16x16x32_bf16(a, bg1, hg[mt][1], 0, 0, 0);
                hu[mt][1] = __builtin_amdgcn_mfma_f32_16x16x32_bf16(a, bu1, hu[mt][1], 0, 0, 0);
            }
        }
    };

    // ---- sH write: silu(g)*u, pair-pack cols via shfl_xor(1), ds_write_b32 ----
    auto writeH = [&]() {
        const int p = rr & 1;
#pragma unroll
        for (int mt = 0; mt < 2; ++mt)
#pragma unroll
            for (int ft = 0; ft < 2; ++ft) {
                float gv0 = hg[mt][ft][0], gv1 = hg[mt][ft][1], gv2 = hg[mt][ft][2], gv3 = hg[mt][ft][3];
                float h0 = gv0 * sigm(gv0) * hu[mt][ft][0];
                float h1 = gv1 * sigm(gv1) * hu[mt][ft][1];
                float h2 = gv2 * sigm(gv2) * hu[mt][ft][2];
                float h3 = gv3 * sigm(gv3) * hu[mt][ft][3];
#pragma unroll
                for (int j = 0; j < 2; ++j) {
                    float own  = p ? (j ? h3 : h2) : (j ? h1 : h0);
                    float sent = p ? (j ? h1 : h0) : (j ? h3 : h2);
                    float recv = __shfl_xor(sent, 1, 64);
                    float lo = p ? recv : own;
                    float hi = p ? own : recv;
                    __hip_bfloat162 pk;
                    pk.x = __float2bfloat16(lo);
                    pk.y = __float2bfloat16(hi);
                    int row = wm * 32 + mt * 16 + kq * 4 + p * 2 + j;
                    int col = wn * 32 + ft * 16 + (rr & ~1);
                    *reinterpret_cast<__hip_bfloat162*>(&sH[row][col]) = pk;
                }
            }
    };

    // ---- phase3: down-GEMM partials over chunk c's K=128 ----
    auto p3 = [&](int c) {
        const __hip_bfloat16* dR = dw + (size_t)(wn * 64 + rr) * D_FFN + c * FC + kr;
#pragma unroll
        for (int kk = 0; kk < 4; ++kk) {
            bf16x8 b0 = *reinterpret_cast<const bf16x8*>(dR + kk * 32);
            bf16x8 b1 = *reinterpret_cast<const bf16x8*>(dR + 16 * D_FFN + kk * 32);
            bf16x8 b2 = *reinterpret_cast<const bf16x8*>(dR + 32 * D_FFN + kk * 32);
            bf16x8 b3 = *reinterpret_cast<const bf16x8*>(dR + 48 * D_FFN + kk * 32);
#pragma unroll
            for (int mt = 0; mt < 2; ++mt) {
                bf16x8 a = *reinterpret_cast<const bf16x8*>(&sH[wm * 32 + mt * 16 + rr][kk * 32 + kr]);
                acc_o[mt][0] = __builtin_amdgcn_mfma_f32_16x16x32_bf16(a, b0, acc_o[mt][0], 0, 0, 0);
                acc_o[mt][1] = __builtin_amdgcn_mfma_f32_16x16x32_bf16(a, b1, acc_o[mt][1], 0, 0, 0);
                acc_o[mt][2] = __builtin_amdgcn_mfma_f32_16x16x32_bf16(a, b2, acc_o[mt][2], 0, 0, 0);
                acc_o[mt][3] = __builtin_amdgcn_mfma_f32_16x16x32_bf16(a, b3, acc_o[mt][3], 0, 0, 0);
            }
        }
    };

    __syncthreads();            // sN staged
    p2compute(0);
    writeH();                   // sH untouched before this, no barrier needed pre-write
    __syncthreads();            // sH(0) ready
    for (int c = 0; c < 8; ++c) {
        p3(c);                  // reads sH(c)
        if (c < 7) p2compute(c + 1);   // independent: global loads + sN reads + MFMA
        __syncthreads();        // p3 reads done
        if (c < 7) {
            writeH();           // overwrite sH with chunk c+1
            __syncthreads();    // sH(c+1) ready
        }
    }

    // epilogue: residual add, f32 store
#pragma unroll
    for (int mt = 0; mt < 2; ++mt)
#pragma unroll
        for (int nt = 0; nt < 4; ++nt)
#pragma unroll
            for (int r = 0; r < 4; ++r) {
                int m = m0 + wm * 32 + mt * 16 + kq * 4 + r;
                int d = wn * 64 + nt * 16 + rr;
                size_t idx = (size_t)m * D_BLADE + d;
                out[idx] = x[idx] + acc_o[mt][nt][r];
            }
}

extern "C" void kernel_launch(void* const* d_in, const int* in_sizes, int n_in,
                              void* d_out, int out_size, void* d_ws, size_t ws_size,
                              hipStream_t stream) {
    const float* x   = (const float*)d_in[0];
    const float* iw  = (const float*)d_in[1];
    const float* sg  = (const float*)d_in[2];
    const float* gg  = (const float*)d_in[3];
    const float* gwf = (const float*)d_in[4];
    const float* uwf = (const float*)d_in[5];
    const float* dwf = (const float*)d_in[6];
    const float* lnw = (const float*)d_in[7];
    const float* lnb = (const float*)d_in[8];
    float* out = (float*)d_out;

    char* ws = (char*)d_ws;
    __hip_bfloat16* nrm = (__hip_bfloat16*)ws;
    __hip_bfloat16* gb  = (__hip_bfloat16*)(ws + (size_t)M_TOTAL * D_BLADE * 2);
    __hip_bfloat16* ub  = gb + (size_t)D_FFN * D_BLADE;
    __hip_bfloat16* db  = ub + (size_t)D_FFN * D_BLADE;

    wconv_kernel<<<dim3((D_FFN * D_BLADE) / 256), dim3(256), 0, stream>>>(gwf, uwf, dwf, gb, ub, db);
    geo_ln_kernel<<<dim3(N_TOK), dim3(256), 0, stream>>>(x, iw, sg, gg, lnw, lnb, nrm);
    ffn_kernel<<<dim3(M_TOTAL / BM), dim3(512), 0, stream>>>(nrm, gb, ub, db, x, out);
}

// Round 3
// 216.191 us; speedup vs baseline: 1.9220x; 1.9220x over previous
//
#include <hip/hip_runtime.h>
#include <hip/hip_bf16.h>

#define D_BLADE 256
#define D_FFN 1024
#define N_TOK 8192
#define M_TOTAL (N_TOK * 8)

#define BM 128
#define SNP 264   // sN row stride (528B = 33 16B-slots -> conflict-free b128 reads)
#define SHP 136   // sH row stride (272B = 17 16B-slots)
#define FC 128    // F per chunk (8 chunks)
#define SN_ELEMS (BM * SNP)
#define SH_ELEMS (BM * SHP)
#define LDS_BYTES ((SN_ELEMS + 2 * SH_ELEMS) * 2)

typedef __attribute__((ext_vector_type(8))) short bf16x8;
typedef __attribute__((ext_vector_type(4))) float f32x4;

__device__ __forceinline__ float sigm(float v) { return 1.0f / (1.0f + __expf(-v)); }

// ---------------- weights fp32 -> bf16 ----------------
__global__ __launch_bounds__(256) void wconv_kernel(const float* __restrict__ g,
                                                    const float* __restrict__ u,
                                                    const float* __restrict__ dn,
                                                    __hip_bfloat16* __restrict__ gb,
                                                    __hip_bfloat16* __restrict__ ub,
                                                    __hip_bfloat16* __restrict__ db) {
    int i = blockIdx.x * 256 + threadIdx.x;
    gb[i] = __float2bfloat16(g[i]);
    ub[i] = __float2bfloat16(u[i]);
    db[i] = __float2bfloat16(dn[i]);
}

// ---------------- geometric product + mix + LayerNorm -> normed (bf16) ----------------
__global__ __launch_bounds__(256) void geo_ln_kernel(
    const float* __restrict__ x, const float* __restrict__ iw,
    const float* __restrict__ sg, const float* __restrict__ gg,
    const float* __restrict__ lnw, const float* __restrict__ lnb,
    __hip_bfloat16* __restrict__ nrm)
{
    static constexpr int CK[64] = {
        0,1,2,3,4,5,6,7,
        1,0,4,5,2,3,7,6,
        2,4,0,6,1,7,3,5,
        3,5,6,0,7,1,2,4,
        4,2,1,7,0,6,5,3,
        5,3,7,1,6,0,4,2,
        6,7,3,2,5,4,0,1,
        7,6,5,4,3,2,1,0};
    __shared__ float coefs[64];
    __shared__ float redA[4][8];
    __shared__ float redB[4][8];
    const int tid = threadIdx.x;
    const int n = blockIdx.x;
    if (tid < 64) coefs[tid] = sg[tid] * sigm(iw[tid]);
    __syncthreads();

    const float* xp = x + (size_t)n * (8 * D_BLADE) + tid;
    float xa[8];
#pragma unroll
    for (int b = 0; b < 8; ++b) xa[b] = xp[b * D_BLADE];

    float geo[8] = {0.f,0.f,0.f,0.f,0.f,0.f,0.f,0.f};
#pragma unroll
    for (int p = 0; p < 64; ++p)
        geo[CK[p]] += coefs[p] * xa[p >> 3] * xa[p & 7];

    const float g = sigm(gg[0]);
    float mixed[8], sm[8], sq[8];
#pragma unroll
    for (int b = 0; b < 8; ++b) {
        mixed[b] = g * geo[b] + (1.0f - g) * xa[b];
        sm[b] = mixed[b];
        sq[b] = mixed[b] * mixed[b];
    }
#pragma unroll
    for (int off = 32; off > 0; off >>= 1) {
#pragma unroll
        for (int b = 0; b < 8; ++b) {
            sm[b] += __shfl_xor(sm[b], off, 64);
            sq[b] += __shfl_xor(sq[b], off, 64);
        }
    }
    const int wv = tid >> 6;
    if ((tid & 63) == 0) {
#pragma unroll
        for (int b = 0; b < 8; ++b) { redA[wv][b] = sm[b]; redB[wv][b] = sq[b]; }
    }
    __syncthreads();

    const float lw = lnw[tid], lb = lnb[tid];
    __hip_bfloat16* op = nrm + ((size_t)n * 8) * D_BLADE + tid;
#pragma unroll
    for (int b = 0; b < 8; ++b) {
        float ts = redA[0][b] + redA[1][b] + redA[2][b] + redA[3][b];
        float tq = redB[0][b] + redB[1][b] + redB[2][b] + redB[3][b];
        float mu = ts * (1.0f / 256.0f);
        float var = tq * (1.0f / 256.0f) - mu * mu;
        float rs = rsqrtf(var + 1e-5f);
        op[b * D_BLADE] = __float2bfloat16((mixed[b] - mu) * rs * lw + lb);
    }
}

// ---------------- fused SwiGLU FFN + residual ----------------
// BM=128, 512 threads = 8 waves. Each wave owns FULL M=128 (8 mt) and a
// disjoint F-slice (p2: F=16 = w*16..) / N-slice (p3: N=32 = w*32..), so every
// weight fragment is loaded exactly once per block (no inter-wave duplication).
// sH double-buffered -> ONE barrier per chunk; p3(c) overlaps p2(c+1).
__global__ __launch_bounds__(512, 2) void ffn_kernel(
    const __hip_bfloat16* __restrict__ nrm,
    const __hip_bfloat16* __restrict__ gw,
    const __hip_bfloat16* __restrict__ uw,
    const __hip_bfloat16* __restrict__ dw,
    const float* __restrict__ x,
    float* __restrict__ out)
{
    extern __shared__ __hip_bfloat16 smem[];
    __hip_bfloat16* sN = smem;                 // [BM][SNP]
    __hip_bfloat16* sHb = smem + SN_ELEMS;     // [2][BM][SHP]

    const int tid = threadIdx.x;
    const int l = tid & 63;
    const int w = tid >> 6;       // 0..7: F-slice (p2) / N-slice (p3)
    const int rr = l & 15;
    const int kq = l >> 4;        // 0..3
    const int kr = kq * 8;
    const int m0 = blockIdx.x * BM;

    // stage normed 128x256 bf16 tile (reg-staged: padded LDS rows)
#pragma unroll
    for (int it = 0; it < 8; ++it) {
        int idx = (it * 512 + tid) * 8;
        int r = idx >> 8, c2 = idx & 255;
        bf16x8 v = *reinterpret_cast<const bf16x8*>(nrm + (size_t)(m0 + r) * D_BLADE + c2);
        *reinterpret_cast<bf16x8*>(&sN[r * SNP + c2]) = v;
    }

    const f32x4 zero = {0.f, 0.f, 0.f, 0.f};
    f32x4 acc[8][2];
#pragma unroll
    for (int mt = 0; mt < 8; ++mt) { acc[mt][0] = zero; acc[mt][1] = zero; }
    f32x4 hg[8], hu[8];

    // ---- phase2: gate/up MFMAs for chunk fc, wave's 16-F stripe, full M=128 ----
    auto p2compute = [&](int fc) {
#pragma unroll
        for (int mt = 0; mt < 8; ++mt) { hg[mt] = zero; hu[mt] = zero; }
        const __hip_bfloat16* gR = gw + (size_t)(fc * FC + w * 16 + rr) * D_BLADE + kr;
        const __hip_bfloat16* uR = uw + (size_t)(fc * FC + w * 16 + rr) * D_BLADE + kr;
#pragma unroll
        for (int kk = 0; kk < 8; ++kk) {
            bf16x8 bg = *reinterpret_cast<const bf16x8*>(gR + kk * 32);
            bf16x8 bu = *reinterpret_cast<const bf16x8*>(uR + kk * 32);
#pragma unroll
            for (int mt = 0; mt < 8; ++mt) {
                bf16x8 a = *reinterpret_cast<const bf16x8*>(&sN[(mt * 16 + rr) * SNP + kk * 32 + kr]);
                hg[mt] = __builtin_amdgcn_mfma_f32_16x16x32_bf16(a, bg, hg[mt], 0, 0, 0);
                hu[mt] = __builtin_amdgcn_mfma_f32_16x16x32_bf16(a, bu, hu[mt], 0, 0, 0);
            }
        }
    };

    // ---- silu(g)*u -> sH[buf]: pair-pack cols via shfl_xor(1), b32 writes (2-way) ----
    auto writeH = [&](int c) {
        __hip_bfloat16* buf = sHb + (c & 1) * SH_ELEMS;
        const int p = rr & 1;
        const int col = w * 16 + (rr & ~1);
#pragma unroll
        for (int mt = 0; mt < 8; ++mt) {
            float g0 = hg[mt][0], g1 = hg[mt][1], g2 = hg[mt][2], g3 = hg[mt][3];
            float h0 = g0 * sigm(g0) * hu[mt][0];
            float h1 = g1 * sigm(g1) * hu[mt][1];
            float h2 = g2 * sigm(g2) * hu[mt][2];
            float h3 = g3 * sigm(g3) * hu[mt][3];
#pragma unroll
            for (int j = 0; j < 2; ++j) {
                float own  = p ? (j ? h3 : h2) : (j ? h1 : h0);
                float sent = p ? (j ? h1 : h0) : (j ? h3 : h2);
                float recv = __shfl_xor(sent, 1, 64);
                float lo = p ? recv : own;
                float hi = p ? own : recv;
                __hip_bfloat162 pk;
                pk.x = __float2bfloat16(lo);
                pk.y = __float2bfloat16(hi);
                int row = mt * 16 + kq * 4 + p * 2 + j;
                *reinterpret_cast<__hip_bfloat162*>(&buf[row * SHP + col]) = pk;
            }
        }
    };

    // ---- phase3: down-GEMM partials, wave's 32-N stripe, full M=128 ----
    auto p3 = [&](int c) {
        const __hip_bfloat16* buf = sHb + (c & 1) * SH_ELEMS;
        const __hip_bfloat16* dR = dw + (size_t)(w * 32 + rr) * D_FFN + c * FC + kr;
#pragma unroll
        for (int kk = 0; kk < 4; ++kk) {
            bf16x8 b0 = *reinterpret_cast<const bf16x8*>(dR + kk * 32);
            bf16x8 b1 = *reinterpret_cast<const bf16x8*>(dR + 16 * D_FFN + kk * 32);
#pragma unroll
            for (int mt = 0; mt < 8; ++mt) {
                bf16x8 a = *reinterpret_cast<const bf16x8*>(&buf[(mt * 16 + rr) * SHP + kk * 32 + kr]);
                acc[mt][0] = __builtin_amdgcn_mfma_f32_16x16x32_bf16(a, b0, acc[mt][0], 0, 0, 0);
                acc[mt][1] = __builtin_amdgcn_mfma_f32_16x16x32_bf16(a, b1, acc[mt][1], 0, 0, 0);
            }
        }
    };

    __syncthreads();            // sN staged
    p2compute(0);
    writeH(0);
    __syncthreads();            // sH(0) ready
    for (int c = 0; c < 8; ++c) {
        p3(c);                              // reads buf[c&1]
        if (c < 7) { p2compute(c + 1); writeH(c + 1); }  // writes buf[(c+1)&1]
        __syncthreads();                    // publish sH(c+1); also fences buf reuse
    }

    // epilogue: residual add, f32 store
#pragma unroll
    for (int mt = 0; mt < 8; ++mt)
#pragma unroll
        for (int nt = 0; nt < 2; ++nt)
#pragma unroll
            for (int r = 0; r < 4; ++r) {
                int m = m0 + mt * 16 + kq * 4 + r;
                int d = w * 32 + nt * 16 + rr;
                size_t idx = (size_t)m * D_BLADE + d;
                out[idx] = x[idx] + acc[mt][nt][r];
            }
}

extern "C" void kernel_launch(void* const* d_in, const int* in_sizes, int n_in,
                              void* d_out, int out_size, void* d_ws, size_t ws_size,
                              hipStream_t stream) {
    const float* x   = (const float*)d_in[0];
    const float* iw  = (const float*)d_in[1];
    const float* sg  = (const float*)d_in[2];
    const float* gg  = (const float*)d_in[3];
    const float* gwf = (const float*)d_in[4];
    const float* uwf = (const float*)d_in[5];
    const float* dwf = (const float*)d_in[6];
    const float* lnw = (const float*)d_in[7];
    const float* lnb = (const float*)d_in[8];
    float* out = (float*)d_out;

    char* ws = (char*)d_ws;
    __hip_bfloat16* nrm = (__hip_bfloat16*)ws;
    __hip_bfloat16* gb  = (__hip_bfloat16*)(ws + (size_t)M_TOTAL * D_BLADE * 2);
    __hip_bfloat16* ub  = gb + (size_t)D_FFN * D_BLADE;
    __hip_bfloat16* db  = ub + (size_t)D_FFN * D_BLADE;

    wconv_kernel<<<dim3((D_FFN * D_BLADE) / 256), dim3(256), 0, stream>>>(gwf, uwf, dwf, gb, ub, db);
    geo_ln_kernel<<<dim3(N_TOK), dim3(256), 0, stream>>>(x, iw, sg, gg, lnw, lnb, nrm);
    ffn_kernel<<<dim3(M_TOTAL / BM), dim3(512), LDS_BYTES, stream>>>(nrm, gb, ub, db, x, out);
}